// Round 3
// baseline (510.922 us; speedup 1.0000x reference)
//
#include <hip/hip_runtime.h>

// FELDMSTM: fused AutoCorrelationLayer(FourierBlock) + FFTDecompLayer
// B=8 N=2000 L=96 D=32 H=4 E=8 modes={1,4,5} kavg=25, float32 in/out.
//
// Math folding (exact):
//   q-bias drops (sum of cos/sin over full period = 0); k,v projections unused.
//   CS[d][m]   = sum_l x[l,d] * {cos,sin}(2*pi*m*l/96)        (forward basis)
//   X[c][m]    = sum_d Wq[c,d] * CS[d][m]   (Xre = Wq*Cx, Xim = -Wq*Sx)
//   O[h,o][m]  = sum_e X[h*8+e][m] * (W1 + i*W2)[n,h,e,o,m]
//   Z[d][m]    = sum_c Wo[d,c] * O[c][m]
//   new_x[l,d] = (1/48) * sum_m (Zre*cos - Zim*sin) + bo[d]
//   xr = x + new_x;  trend = 25-tap edge-padded mean;  res = xr - trend.
//
// R3 vs R1 (158us/dispatch): R1 is LDS-PIPE-bound (~6.1k cyc/block of DS
// traffic == observed block throughput; conflicts 848cy/block from phase-D
// W1_s/W2_s 4-way-conflicted reads since 192*h===0 mod 32). R2's forced
// occupancy (launch_bounds(512,8)) spilled xv/xr/lowv to scratch
// (WRITE_SIZE 192->479MB) -- reverted. R3 keeps R1's structure but removes
// ALL weight arrays from LDS: solo phases read Wq/Wo rows as float4 and
// W1/W2 scalars straight from global (L2/L3-hot; VMEM pipe was 27% idle).
// Kills weight staging (14 ds_writes + 15 gloads/thread), 80 solo LDS
// reads, and the whole phase-D conflict source. LDS 31.2KB -> 16.6KB ->
// 8 blocks/CU (wave cap). launch_bounds(256,6): no spill risk (R1: 44 VGPR).

#define N_NODES 2000

__global__ __launch_bounds__(256, 6)
void fused_fourier_decomp(const float* __restrict__ x,
                          const float* __restrict__ Wq,
                          const float* __restrict__ Wo,
                          const float* __restrict__ bo,
                          const float* __restrict__ W1,
                          const float* __restrict__ W2,
                          float* __restrict__ out)
{
  // xT: xr staging, stride 97 -> bank (d + l) % 32, conflict-free column sweeps.
  // Aliases: pp = xT[0..1535] (phase-B partials; dead after solo reduce),
  //          sbuf = xT[1600..2111] (solo spectral scratch; dead before F).
  // xT is first written as xr in phase F, strictly after the last sbuf read.
  __shared__ __align__(16) float xT[32 * 97];     // 12416 B
  __shared__ __align__(16) float basis[96 * 8];   // [l][0..2]=cos_m, [3..5]=sin_m
  __shared__ __align__(16) float Z_s[32 * 8];     // [dout][0..2]=re, [3..5]=im
  __shared__ float bo_s[32];
  float* const pp = xT;                           // 1536 floats used
  float* const sbuf = xT + 1600;                  // 512 floats used

  const int t = threadIdx.x;
  const int bid = blockIdx.x;           // b*N + n
  const int n = bid % N_NODES;
  const size_t base = (size_t)bid * (96 * 32);

  const int d = t & 31;                 // owned channel / column
  const int g = t >> 5;                 // l-chunk 0..7 (12 rows each)
  const int l0 = g * 12;

  // ---- load x slice into registers: thread owns column d, rows l0..l0+11.
  // Lanes 0..31 read 128 contiguous bytes of row l0 (fully coalesced).
  float xv[12];
#pragma unroll
  for (int i = 0; i < 12; ++i)
    xv[i] = x[base + (size_t)(l0 + i) * 32 + d];

  if (t < 32) bo_s[t] = bo[t];

  // ---- cos/sin basis (exact integer angle reduction, precise sincos)
  if (t < 96) {
    const int modes[3] = {1, 4, 5};
#pragma unroll
    for (int m = 0; m < 3; ++m) {
      int r = (modes[m] * t) % 96;
      float ang = (float)r * (6.28318530717958647692f / 96.0f);
      float sv, cv;
      sincosf(ang, &sv, &cv);
      basis[t * 8 + m] = cv;
      basis[t * 8 + 3 + m] = sv;
    }
    basis[t * 8 + 6] = 0.0f;
    basis[t * 8 + 7] = 0.0f;
  }
  __syncthreads();   // barrier #1: basis + bo ready

  // ---- phase B: partial CS over own 12 rows (x from registers)
  {
    float a0 = 0.f, a1 = 0.f, a2 = 0.f, a3 = 0.f, a4 = 0.f, a5 = 0.f;
#pragma unroll
    for (int i = 0; i < 12; ++i) {
      const int l = l0 + i;
      const float4 b0 = *(const float4*)&basis[l * 8];
      const float2 b1 = *(const float2*)&basis[l * 8 + 4];
      const float v = xv[i];
      a0 = fmaf(v, b0.x, a0);
      a1 = fmaf(v, b0.y, a1);
      a2 = fmaf(v, b0.z, a2);
      a3 = fmaf(v, b0.w, a3);
      a4 = fmaf(v, b1.x, a4);
      a5 = fmaf(v, b1.y, a5);
    }
    pp[g * 192 + 0 * 32 + d] = a0;
    pp[g * 192 + 1 * 32 + d] = a1;
    pp[g * 192 + 2 * 32 + d] = a2;
    pp[g * 192 + 3 * 32 + d] = a3;
    pp[g * 192 + 4 * 32 + d] = a4;
    pp[g * 192 + 5 * 32 + d] = a5;
  }
  __syncthreads();   // barrier #2: pp ready

  // ---- wave-0 solo spectral section: reduce -> C -> D -> E (no block syncs;
  // DS ops from one wave complete in issue order; wave_barrier stops the
  // compiler from reordering across sub-phases). Weights come from global
  // (L2/L3-hot), NOT LDS -- keeps the per-CU LDS pipe for x/xr traffic.
  if (t < 64) {
    const int c  = t & 31;          // channel this lane owns in each stage
    const int jj = t >> 5;          // 0: real half, 1: imag half
    float* const csb = sbuf;        // [32][8] raw CS (cos sums | sin sums)
    float* const xsb = sbuf + 256;  // [32][8] X (imag already sign-flipped)
    float* const osb = sbuf;        // reuse csb region after phase C

    // reduce: CS[d][j] = sum_g pp[g][j][d]   (g ascending = original order)
#pragma unroll
    for (int k = 0; k < 3; ++k) {
      const int j = jj * 3 + k;
      float s = 0.f;
#pragma unroll
      for (int gg = 0; gg < 8; ++gg) s += pp[gg * 192 + j * 32 + c];
      csb[c * 8 + j] = s;
    }
    __builtin_amdgcn_wave_barrier();

    // phase C: X = Wq * CS ; Xim picks up the rfft minus sign.
    // Wq row c read as 8 float4 from global (4KB, L2-hot for every block).
    {
      const float* wqr = Wq + c * 32;
      float X0 = 0.f, X1 = 0.f, X2 = 0.f;
#pragma unroll
      for (int q = 0; q < 8; ++q) {
        const float4 w = *(const float4*)&wqr[q * 4];
        const int d0 = q * 4;
        const int cb0 = (d0 + 0) * 8 + jj * 3;
        const int cb1 = (d0 + 1) * 8 + jj * 3;
        const int cb2 = (d0 + 2) * 8 + jj * 3;
        const int cb3 = (d0 + 3) * 8 + jj * 3;
        X0 = fmaf(w.x, csb[cb0 + 0], X0);
        X1 = fmaf(w.x, csb[cb0 + 1], X1);
        X2 = fmaf(w.x, csb[cb0 + 2], X2);
        X0 = fmaf(w.y, csb[cb1 + 0], X0);
        X1 = fmaf(w.y, csb[cb1 + 1], X1);
        X2 = fmaf(w.y, csb[cb1 + 2], X2);
        X0 = fmaf(w.z, csb[cb2 + 0], X0);
        X1 = fmaf(w.z, csb[cb2 + 1], X1);
        X2 = fmaf(w.z, csb[cb2 + 2], X2);
        X0 = fmaf(w.w, csb[cb3 + 0], X0);
        X1 = fmaf(w.w, csb[cb3 + 1], X1);
        X2 = fmaf(w.w, csb[cb3 + 2], X2);
      }
      const float sgn = jj ? -1.f : 1.f;
      xsb[c * 8 + jj * 3 + 0] = sgn * X0;
      xsb[c * 8 + jj * 3 + 1] = sgn * X1;
      xsb[c * 8 + jj * 3 + 2] = sgn * X2;
    }
    __builtin_amdgcn_wave_barrier();

    // phase D: per-head complex contraction over e (einsum bnhem,nheom).
    // jj=0 lanes produce Re(O[h,o][m]), jj=1 lanes produce Im(O[h,o][m]).
    // W1/W2 scalars read from global (per-n 6KB, L3-resident; lanes 32-63
    // duplicate lanes 0-31's addresses -> coalescer dedupes).
    {
      const int h = (t >> 3) & 3;
      const int o = t & 7;
      const float* w1p = W1 + (size_t)n * 768 + h * 192 + o * 3;
      const float* w2p = W2 + (size_t)n * 768 + h * 192 + o * 3;
      float od0 = 0.f, od1 = 0.f, od2 = 0.f;
#pragma unroll
      for (int e = 0; e < 8; ++e) {
        const int cp = h * 8 + e;
        const float4 xa = *(const float4*)&xsb[cp * 8];     // Xre0,Xre1,Xre2,Xim0
        const float2 xb = *(const float2*)&xsb[cp * 8 + 4]; // Xim1,Xim2
        const float w1_0 = w1p[e * 24 + 0];
        const float w1_1 = w1p[e * 24 + 1];
        const float w1_2 = w1p[e * 24 + 2];
        const float w2_0 = w2p[e * 24 + 0];
        const float w2_1 = w2p[e * 24 + 1];
        const float w2_2 = w2p[e * 24 + 2];
        {  // m = 0
          const float a = jj ? w1_0 : -w2_0;   // coeff on Xim
          const float b = jj ? w2_0 : w1_0;    // coeff on Xre
          od0 = fmaf(xa.x, b, fmaf(xa.w, a, od0));
        }
        {  // m = 1
          const float a = jj ? w1_1 : -w2_1;
          const float b = jj ? w2_1 : w1_1;
          od1 = fmaf(xa.y, b, fmaf(xb.x, a, od1));
        }
        {  // m = 2
          const float a = jj ? w1_2 : -w2_2;
          const float b = jj ? w2_2 : w1_2;
          od2 = fmaf(xa.z, b, fmaf(xb.y, a, od2));
        }
      }
      const int cp = h * 8 + o;
      osb[cp * 8 + jj * 3 + 0] = od0;
      osb[cp * 8 + jj * 3 + 1] = od1;
      osb[cp * 8 + jj * 3 + 2] = od2;
    }
    __builtin_amdgcn_wave_barrier();

    // phase E: Z = Wo * O  (fold output projection into spectrum).
    // Wo row c read as 8 float4 from global (4KB, L2-hot).
    {
      const float* wor = Wo + c * 32;
      float z0 = 0.f, z1 = 0.f, z2 = 0.f;
#pragma unroll
      for (int q = 0; q < 8; ++q) {
        const float4 w = *(const float4*)&wor[q * 4];
        const int c0 = q * 4;
        const int ob0 = (c0 + 0) * 8 + jj * 3;
        const int ob1 = (c0 + 1) * 8 + jj * 3;
        const int ob2 = (c0 + 2) * 8 + jj * 3;
        const int ob3 = (c0 + 3) * 8 + jj * 3;
        z0 = fmaf(w.x, osb[ob0 + 0], z0);
        z1 = fmaf(w.x, osb[ob0 + 1], z1);
        z2 = fmaf(w.x, osb[ob0 + 2], z2);
        z0 = fmaf(w.y, osb[ob1 + 0], z0);
        z1 = fmaf(w.y, osb[ob1 + 1], z1);
        z2 = fmaf(w.y, osb[ob1 + 2], z2);
        z0 = fmaf(w.z, osb[ob2 + 0], z0);
        z1 = fmaf(w.z, osb[ob2 + 1], z1);
        z2 = fmaf(w.z, osb[ob2 + 2], z2);
        z0 = fmaf(w.w, osb[ob3 + 0], z0);
        z1 = fmaf(w.w, osb[ob3 + 1], z1);
        z2 = fmaf(w.w, osb[ob3 + 2], z2);
      }
      Z_s[c * 8 + jj * 3 + 0] = z0;
      Z_s[c * 8 + jj * 3 + 1] = z1;
      Z_s[c * 8 + jj * 3 + 2] = z2;
    }
  }
  __syncthreads();   // barrier #3: Z_s ready

  // ---- phase F: irfft synthesis + out-bias + residual -> xr (regs + LDS)
  float xr[12];
  {
    const float4 z0 = *(const float4*)&Z_s[d * 8];     // (re0,re1,re2,im0)
    const float2 z1 = *(const float2*)&Z_s[d * 8 + 4]; // (im1,im2)
    const float bov = bo_s[d];
#pragma unroll
    for (int i = 0; i < 12; ++i) {
      const int l = l0 + i;
      const float4 b0 = *(const float4*)&basis[l * 8];     // (c0,c1,c2,s0)
      const float2 b1 = *(const float2*)&basis[l * 8 + 4]; // (s1,s2)
      const float v = z0.x * b0.x + z0.y * b0.y + z0.z * b0.z
                    - z0.w * b0.w - z1.x * b1.x - z1.y * b1.y;
      const float r = fmaf(v, (1.0f / 48.0f), bov) + xv[i];
      xr[i] = r;
      xT[d * 97 + l] = r;
    }
  }
  __syncthreads();   // barrier #4: xT ready

  // ---- phase G: 25-tap edge-padded moving average (running window) + store
  {
    const float* col = &xT[d * 97];
    float lowv[12];
    float S = 0.f;
#pragma unroll
    for (int j = 0; j < 12; ++j) {          // below-window taps l0-12..l0-1 (clamped)
      int idx = l0 - 12 + j;
      idx = idx < 0 ? 0 : idx;
      lowv[j] = col[idx];
      S += lowv[j];
    }
#pragma unroll
    for (int i = 0; i < 12; ++i) S += xr[i]; // own rows l0..l0+11
    {
      int idx = l0 + 12;                     // top tap of first window
      idx = idx > 95 ? 95 : idx;
      S += col[idx];
    }
#pragma unroll
    for (int i = 0; i < 12; ++i) {
      const int l = l0 + i;
      const float res = xr[i] - S * (1.0f / 25.0f);
      out[base + (size_t)l * 32 + d] = res;
      // slide window: drop clamp(l-12), add clamp(l+13)
      int hi = l + 13;
      hi = hi > 95 ? 95 : hi;
      S += col[hi] - lowv[i];
    }
  }
}

extern "C" void kernel_launch(void* const* d_in, const int* in_sizes, int n_in,
                              void* d_out, int out_size, void* d_ws, size_t ws_size,
                              hipStream_t stream) {
  (void)n_in; (void)out_size; (void)d_ws; (void)ws_size;
  const float* x  = (const float*)d_in[0];
  const float* Wq = (const float*)d_in[1];
  // d_in[2]=bq (exactly cancelled), d_in[3..6]=Wk,bk,Wv,bv (unused by output)
  const float* Wo = (const float*)d_in[7];
  const float* bo = (const float*)d_in[8];
  const float* W1 = (const float*)d_in[9];
  const float* W2 = (const float*)d_in[10];
  float* out = (float*)d_out;

  const int blocks = in_sizes[0] / (96 * 32);  // B*N tiles of 96x32
  fused_fourier_decomp<<<blocks, 256, 0, stream>>>(x, Wq, Wo, bo, W1, W2, out);
}

// Round 5
// 387.538 us; speedup vs baseline: 1.3184x; 1.3184x over previous
//
#include <hip/hip_runtime.h>

// FELDMSTM: fused AutoCorrelationLayer(FourierBlock) + FFTDecompLayer
// B=8 N=2000 L=96 D=32 H=4 E=8 modes={1,4,5} kavg=25, float32 in/out.
//
// Math folding (exact):
//   q-bias drops (sum of cos/sin over full period = 0); k,v projections unused.
//   CS[d][m]   = sum_l x[l,d] * {cos,sin}(2*pi*m*l/96)        (forward basis)
//   X[c][m]    = sum_d Wq[c,d] * CS[d][m]   (Xre = Wq*Cx, Xim = -Wq*Sx)
//   O[h,o][m]  = sum_e X[h*8+e][m] * (W1 + i*W2)[n,h,e,o,m]
//   Z[d][m]    = sum_c Wo[d,c] * O[c][m]
//   new_x[l,d] = (1/48) * sum_m (Zre*cos - Zim*sin) + bo[d]
//   xr = x + new_x;  trend = 25-tap edge-padded mean;  res = xr - trend.
//
// R4 = R1 (158us/dispatch anchor) + solo-section LDS diet. Model: R1 is
// LDS-pipe-bound (~800 wave DS instrs/block ~= 6.1k cyc observed); solo
// section was ~360 of them, mostly scalar. Changes:
//  - spectral scratch j-major [6][32] -> C/E read broadcast float4 (96->24)
//  - reduce vectorized: 48 lanes x 8 ds_read_b128
//  - W1/W2 staged interleaved W12_s[cp*68+e*8+..] (16B-aligned, bank-stride
//    4cp conflict-free) -> D reads 16 vector ops (was 48 4-way-conflicted)
//  - Wq/Wo rows as float4 from global in solo wave (L2-hot; VMEM idle);
//    their LDS arrays deleted -> LDS 31.2 -> 24.75 KB -> 6 blocks/CU
//  - launch_bounds(256,4) restored: R2(512,8)/R3(256,6) both forced spills
//    (WRITE_SIZE 2x output); R1's (256,4)/44VGPR wrote exactly 192000 KB.
// Accumulation orders identical to R1 (bitwise-comparable numerics).
// (R4 resubmission: previous round was an infra failure, kernel never ran.)

#define N_NODES 2000

__global__ __launch_bounds__(256, 4)
void fused_fourier_decomp(const float* __restrict__ x,
                          const float* __restrict__ Wq,
                          const float* __restrict__ Wo,
                          const float* __restrict__ bo,
                          const float* __restrict__ W1,
                          const float* __restrict__ W2,
                          float* __restrict__ out)
{
  // xT: xr staging, stride 97 -> bank (d + l) % 32, conflict-free column sweeps.
  // Aliases inside xT (all dead before phase F first writes xT):
  //   pp  = xT[0..1535]     phase-B partials (dead after solo reduce)
  //   csb = xT[1600..1791]  [6][32] raw CS (cos|sin, j-major)
  //   xsb = xT[1792..1983]  [6][32] X (sign-applied, j-major)
  //   osb = csb             [6][32] O (reuse after C's last csb read)
  __shared__ __align__(16) float xT[32 * 97];     // 12416 B
  __shared__ __align__(16) float basis[96 * 8];   // [l][0..2]=cos_m, [3..5]=sin_m
  __shared__ __align__(16) float W12_s[32 * 68];  // [cp][e][w1m0..2,w2m0..2,pad2]
  __shared__ __align__(16) float Z_s[32 * 8];     // [dout][0..2]=re, [3..5]=im
  __shared__ float bo_s[32];
  float* const pp  = xT;
  float* const csb = xT + 1600;
  float* const xsb = xT + 1792;
  float* const osb = xT + 1600;   // alias csb

  const int t = threadIdx.x;
  const int bid = blockIdx.x;           // b*N + n
  const int n = bid % N_NODES;
  const size_t base = (size_t)bid * (96 * 32);

  const int d = t & 31;                 // owned channel / column
  const int g = t >> 5;                 // l-chunk 0..7 (12 rows each)
  const int l0 = g * 12;

  // ---- load x slice into registers: thread owns column d, rows l0..l0+11.
  float xv[12];
#pragma unroll
  for (int i = 0; i < 12; ++i)
    xv[i] = x[base + (size_t)(l0 + i) * 32 + d];

  // ---- stage W1/W2 interleaved for phase-D vector reads:
  // src i = h*192 + e*24 + o*3 + m  ->  dst = (h*8+o)*68 + e*8 + m (+3 for W2)
  {
    const float* W1p = W1 + (size_t)n * 768;
    const float* W2p = W2 + (size_t)n * 768;
    for (int i = t; i < 768; i += 256) {
      const int m = i % 3;
      const int o = (i / 3) & 7;
      const int e = (i / 24) & 7;
      const int h = i / 192;
      const int dst = (h * 8 + o) * 68 + e * 8 + m;
      W12_s[dst]     = W1p[i];
      W12_s[dst + 3] = W2p[i];
    }
  }
  if (t < 32) bo_s[t] = bo[t];

  // ---- cos/sin basis (exact integer angle reduction, precise sincos)
  if (t < 96) {
    const int modes[3] = {1, 4, 5};
#pragma unroll
    for (int m = 0; m < 3; ++m) {
      int r = (modes[m] * t) % 96;
      float ang = (float)r * (6.28318530717958647692f / 96.0f);
      float sv, cv;
      sincosf(ang, &sv, &cv);
      basis[t * 8 + m] = cv;
      basis[t * 8 + 3 + m] = sv;
    }
    basis[t * 8 + 6] = 0.0f;
    basis[t * 8 + 7] = 0.0f;
  }
  __syncthreads();   // barrier #1: staging + basis ready

  // ---- phase B: partial CS over own 12 rows (x from registers)
  {
    float a0 = 0.f, a1 = 0.f, a2 = 0.f, a3 = 0.f, a4 = 0.f, a5 = 0.f;
#pragma unroll
    for (int i = 0; i < 12; ++i) {
      const int l = l0 + i;
      const float4 b0 = *(const float4*)&basis[l * 8];
      const float2 b1 = *(const float2*)&basis[l * 8 + 4];
      const float v = xv[i];
      a0 = fmaf(v, b0.x, a0);
      a1 = fmaf(v, b0.y, a1);
      a2 = fmaf(v, b0.z, a2);
      a3 = fmaf(v, b0.w, a3);
      a4 = fmaf(v, b1.x, a4);
      a5 = fmaf(v, b1.y, a5);
    }
    pp[g * 192 + 0 * 32 + d] = a0;
    pp[g * 192 + 1 * 32 + d] = a1;
    pp[g * 192 + 2 * 32 + d] = a2;
    pp[g * 192 + 3 * 32 + d] = a3;
    pp[g * 192 + 4 * 32 + d] = a4;
    pp[g * 192 + 5 * 32 + d] = a5;
  }
  __syncthreads();   // barrier #2: pp ready

  // ---- wave-0 solo spectral section: reduce -> C -> D -> E (no block syncs;
  // DS ops from one wave complete in issue order; wave_barrier stops the
  // compiler from reordering across sub-phases).
  if (t < 64) {
    const int c  = t & 31;          // channel this lane owns in C/E
    const int jj = t >> 5;          // 0: real half, 1: imag half

    // reduce: csb[j][c] = sum_g pp[g][j][c], vectorized: 48 lanes x 8 b128
    if (t < 48) {
      const int j = t >> 3, cq = t & 7;
      float4 acc = make_float4(0.f, 0.f, 0.f, 0.f);
#pragma unroll
      for (int gg = 0; gg < 8; ++gg) {
        const float4 p = *(const float4*)&pp[gg * 192 + j * 32 + cq * 4];
        acc.x += p.x; acc.y += p.y; acc.z += p.z; acc.w += p.w;
      }
      *(float4*)&csb[j * 32 + cq * 4] = acc;
    }
    __builtin_amdgcn_wave_barrier();

    // phase C: X = Wq * CS ; Xim picks up the rfft minus sign.
    // Wq row c as 8 float4 from global (4KB, L2-hot); csb reads broadcast f4.
    {
      const float* wqr = Wq + c * 32;
      float4 wq4[8];
#pragma unroll
      for (int q = 0; q < 8; ++q) wq4[q] = *(const float4*)&wqr[q * 4];
      const int jb = jj * 3;
      float X0 = 0.f, X1 = 0.f, X2 = 0.f;
#pragma unroll
      for (int q = 0; q < 8; ++q) {
        const float4 w  = wq4[q];
        const float4 c0 = *(const float4*)&csb[(jb + 0) * 32 + q * 4];
        const float4 c1 = *(const float4*)&csb[(jb + 1) * 32 + q * 4];
        const float4 c2 = *(const float4*)&csb[(jb + 2) * 32 + q * 4];
        X0 = fmaf(w.x, c0.x, X0); X0 = fmaf(w.y, c0.y, X0);
        X0 = fmaf(w.z, c0.z, X0); X0 = fmaf(w.w, c0.w, X0);
        X1 = fmaf(w.x, c1.x, X1); X1 = fmaf(w.y, c1.y, X1);
        X1 = fmaf(w.z, c1.z, X1); X1 = fmaf(w.w, c1.w, X1);
        X2 = fmaf(w.x, c2.x, X2); X2 = fmaf(w.y, c2.y, X2);
        X2 = fmaf(w.z, c2.z, X2); X2 = fmaf(w.w, c2.w, X2);
      }
      const float sgn = jj ? -1.f : 1.f;
      xsb[(jb + 0) * 32 + c] = sgn * X0;
      xsb[(jb + 1) * 32 + c] = sgn * X1;
      xsb[(jb + 2) * 32 + c] = sgn * X2;
    }
    __builtin_amdgcn_wave_barrier();

    // phase D: per-head complex contraction over e (einsum bnhem,nheom).
    // jj=0 lanes -> Re(O[h,o][m]); jj=1 lanes -> Im(O[h,o][m]).
    {
      const int h = (t >> 3) & 3;
      const int o = t & 7;
      const int cp = h * 8 + o;
      const float* wrow = &W12_s[cp * 68];
      float od0 = 0.f, od1 = 0.f, od2 = 0.f;

#define DSTEP(XC, E_) do {                                                  \
        const float4 wa = *(const float4*)&wrow[(E_) * 8];     /* w1m0..2,w2m0 */ \
        const float2 wb = *(const float2*)&wrow[(E_) * 8 + 4]; /* w2m1,w2m2 */    \
        { const float a = jj ? wa.x : -wa.w; const float b = jj ? wa.w : wa.x;    \
          od0 = fmaf(xr0.XC, b, fmaf(xi0.XC, a, od0)); }                          \
        { const float a = jj ? wa.y : -wb.x; const float b = jj ? wb.x : wa.y;    \
          od1 = fmaf(xr1.XC, b, fmaf(xi1.XC, a, od1)); }                          \
        { const float a = jj ? wa.z : -wb.y; const float b = jj ? wb.y : wa.z;    \
          od2 = fmaf(xr2.XC, b, fmaf(xi2.XC, a, od2)); }                          \
      } while (0)

      {  // e = 0..3
        const float4 xr0 = *(const float4*)&xsb[0 * 32 + h * 8];
        const float4 xr1 = *(const float4*)&xsb[1 * 32 + h * 8];
        const float4 xr2 = *(const float4*)&xsb[2 * 32 + h * 8];
        const float4 xi0 = *(const float4*)&xsb[3 * 32 + h * 8];
        const float4 xi1 = *(const float4*)&xsb[4 * 32 + h * 8];
        const float4 xi2 = *(const float4*)&xsb[5 * 32 + h * 8];
        DSTEP(x, 0); DSTEP(y, 1); DSTEP(z, 2); DSTEP(w, 3);
      }
      {  // e = 4..7
        const float4 xr0 = *(const float4*)&xsb[0 * 32 + h * 8 + 4];
        const float4 xr1 = *(const float4*)&xsb[1 * 32 + h * 8 + 4];
        const float4 xr2 = *(const float4*)&xsb[2 * 32 + h * 8 + 4];
        const float4 xi0 = *(const float4*)&xsb[3 * 32 + h * 8 + 4];
        const float4 xi1 = *(const float4*)&xsb[4 * 32 + h * 8 + 4];
        const float4 xi2 = *(const float4*)&xsb[5 * 32 + h * 8 + 4];
        DSTEP(x, 4); DSTEP(y, 5); DSTEP(z, 6); DSTEP(w, 7);
      }
#undef DSTEP

      osb[(jj * 3 + 0) * 32 + cp] = od0;
      osb[(jj * 3 + 1) * 32 + cp] = od1;
      osb[(jj * 3 + 2) * 32 + cp] = od2;
    }
    __builtin_amdgcn_wave_barrier();

    // phase E: Z = Wo * O (fold output projection into spectrum).
    // Wo row c as 8 float4 from global (L2-hot); osb reads broadcast f4.
    {
      const float* wor = Wo + c * 32;
      float4 wo4[8];
#pragma unroll
      for (int q = 0; q < 8; ++q) wo4[q] = *(const float4*)&wor[q * 4];
      const int jb = jj * 3;
      float Z0 = 0.f, Z1 = 0.f, Z2 = 0.f;
#pragma unroll
      for (int q = 0; q < 8; ++q) {
        const float4 w  = wo4[q];
        const float4 o0 = *(const float4*)&osb[(jb + 0) * 32 + q * 4];
        const float4 o1 = *(const float4*)&osb[(jb + 1) * 32 + q * 4];
        const float4 o2 = *(const float4*)&osb[(jb + 2) * 32 + q * 4];
        Z0 = fmaf(w.x, o0.x, Z0); Z0 = fmaf(w.y, o0.y, Z0);
        Z0 = fmaf(w.z, o0.z, Z0); Z0 = fmaf(w.w, o0.w, Z0);
        Z1 = fmaf(w.x, o1.x, Z1); Z1 = fmaf(w.y, o1.y, Z1);
        Z1 = fmaf(w.z, o1.z, Z1); Z1 = fmaf(w.w, o1.w, Z1);
        Z2 = fmaf(w.x, o2.x, Z2); Z2 = fmaf(w.y, o2.y, Z2);
        Z2 = fmaf(w.z, o2.z, Z2); Z2 = fmaf(w.w, o2.w, Z2);
      }
      Z_s[c * 8 + jb + 0] = Z0;
      Z_s[c * 8 + jb + 1] = Z1;
      Z_s[c * 8 + jb + 2] = Z2;
    }
  }
  __syncthreads();   // barrier #3: Z_s ready

  // ---- phase F: irfft synthesis + out-bias + residual -> xr (regs + LDS)
  float xr[12];
  {
    const float4 z0 = *(const float4*)&Z_s[d * 8];     // (re0,re1,re2,im0)
    const float2 z1 = *(const float2*)&Z_s[d * 8 + 4]; // (im1,im2)
    const float bov = bo_s[d];
#pragma unroll
    for (int i = 0; i < 12; ++i) {
      const int l = l0 + i;
      const float4 b0 = *(const float4*)&basis[l * 8];     // (c0,c1,c2,s0)
      const float2 b1 = *(const float2*)&basis[l * 8 + 4]; // (s1,s2)
      const float v = z0.x * b0.x + z0.y * b0.y + z0.z * b0.z
                    - z0.w * b0.w - z1.x * b1.x - z1.y * b1.y;
      const float r = fmaf(v, (1.0f / 48.0f), bov) + xv[i];
      xr[i] = r;
      xT[d * 97 + l] = r;
    }
  }
  __syncthreads();   // barrier #4: xT ready

  // ---- phase G: 25-tap edge-padded moving average (running window) + store
  {
    const float* col = &xT[d * 97];
    float lowv[12];
    float S = 0.f;
#pragma unroll
    for (int j = 0; j < 12; ++j) {          // below-window taps l0-12..l0-1 (clamped)
      int idx = l0 - 12 + j;
      idx = idx < 0 ? 0 : idx;
      lowv[j] = col[idx];
      S += lowv[j];
    }
#pragma unroll
    for (int i = 0; i < 12; ++i) S += xr[i]; // own rows l0..l0+11
    {
      int idx = l0 + 12;                     // top tap of first window
      idx = idx > 95 ? 95 : idx;
      S += col[idx];
    }
#pragma unroll
    for (int i = 0; i < 12; ++i) {
      const int l = l0 + i;
      const float res = xr[i] - S * (1.0f / 25.0f);
      out[base + (size_t)l * 32 + d] = res;
      // slide window: drop clamp(l-12), add clamp(l+13)
      int hi = l + 13;
      hi = hi > 95 ? 95 : hi;
      S += col[hi] - lowv[i];
    }
  }
}

extern "C" void kernel_launch(void* const* d_in, const int* in_sizes, int n_in,
                              void* d_out, int out_size, void* d_ws, size_t ws_size,
                              hipStream_t stream) {
  (void)n_in; (void)out_size; (void)d_ws; (void)ws_size;
  const float* x  = (const float*)d_in[0];
  const float* Wq = (const float*)d_in[1];
  // d_in[2]=bq (exactly cancelled), d_in[3..6]=Wk,bk,Wv,bv (unused by output)
  const float* Wo = (const float*)d_in[7];
  const float* bo = (const float*)d_in[8];
  const float* W1 = (const float*)d_in[9];
  const float* W2 = (const float*)d_in[10];
  float* out = (float*)d_out;

  const int blocks = in_sizes[0] / (96 * 32);  // B*N tiles of 96x32
  fused_fourier_decomp<<<blocks, 256, 0, stream>>>(x, Wq, Wo, bo, W1, W2, out);
}